// Round 10
// baseline (314.216 us; speedup 1.0000x reference)
//
#include <hip/hip_runtime.h>

#define B_    4096
#define P_    64
#define OBS_  128
#define HID_  256
#define ACTD_ 32

typedef __attribute__((ext_vector_type(8)))  __bf16 bf16x8;
typedef __attribute__((ext_vector_type(2)))  __bf16 bf16x2_t;
typedef __attribute__((ext_vector_type(4)))  float  f32x4;
typedef __attribute__((ext_vector_type(16))) float  f32x16;

#define XSTRIDE 264   // bf16 elems; 33 16B-units/row -> odd mod 8 -> bank-group-balanced

// ws layout (bf16 elems)
#define WS1 0L
#define WS2 2097152L
#define WS3 6291456L
#define WS4 10485760L

#if defined(__has_builtin)
#if __has_builtin(__builtin_amdgcn_cvt_pk_bf16_f32)
#define HAVE_CVT_PK_BF16 1
#endif
#endif
#ifndef HAVE_CVT_PK_BF16
#define HAVE_CVT_PK_BF16 0
#endif

// Integer RNE fp32->bf16. PROVEN on HW (rounds 2/6/7/8/9, absmax 0.0390625).
__device__ __forceinline__ unsigned short f2bf(float x) {
    unsigned u = __builtin_bit_cast(unsigned, x);
    u = (u + 0x7fffu + ((u >> 16) & 1u)) >> 16;   // RNE
    return (unsigned short)u;
}

// Pack two fp32 -> bf16x2 (RNE): lo16 = bf16(a), hi16 = bf16(b).
// HW packed cvt when available (1 instr), else the proven integer path.
__device__ __forceinline__ unsigned pack_bf16_rne(float a, float b) {
#if HAVE_CVT_PK_BF16
    bf16x2_t p = __builtin_amdgcn_cvt_pk_bf16_f32(a, b);
    return __builtin_bit_cast(unsigned, p);
#else
    unsigned ua = __builtin_bit_cast(unsigned, a);
    unsigned ub = __builtin_bit_cast(unsigned, b);
    ua = ua + 0x7fffu + ((ua >> 16) & 1u);
    ub = ub + 0x7fffu + ((ub >> 16) & 1u);
    return __builtin_amdgcn_perm(ub, ua, 0x07060302u);
#endif
}

// ELU via raw inline asm — PROVEN rounds 8/9. Compiler-generated
// unconditional-exp+select ELUs miscompute (rounds 3/4/5); do not revert.
__device__ __forceinline__ float elu_asm(float v) {
    float r;
    asm volatile(
        "v_mul_f32 %0, 0x3fb8aa3b, %1\n\t"   // v * log2(e)
        "v_exp_f32 %0, %0\n\t"               // 2^x (trans pipe)
        "s_nop 1\n\t"                        // trans-result hazard slot
        "v_add_f32 %0, -1.0, %0\n\t"
        "v_cmp_lt_f32 vcc, 0, %1\n\t"
        "v_cndmask_b32 %0, %0, %1, vcc"
        : "=&v"(r) : "v"(v) : "vcc");
    return r;
}

// -------- fused weight prep: fp32 [P][K][N] -> bf16 [P][K/32][4 u][N][8 j] --------
// PERM: layer input comes from a layer256 epilogue storing activation col n at
// position pi(n) (pi(blk+ct*32+l5) = blk+2*l5+ct); image k-rows permuted by pi^-1.
template<int K, int N, bool PERM>
__device__ __forceinline__ void prep_body(const float* __restrict__ W,
                                          unsigned short* __restrict__ out,
                                          int b, int t)
{
    constexpr int CH = K / 32;
    int tid  = b * 256 + t;
    int n    = tid % N;
    int rest = tid / N;
    int u    = rest % 4;
    rest    /= 4;
    int c    = rest % CH;
    int p    = rest / CH;
    unsigned short tmp[8];
#pragma unroll
    for (int j = 0; j < 8; ++j) {
        int sk = c * 32 + u * 8 + j;
        int k  = PERM ? ((sk & ~63) | ((sk & 1) << 5) | ((sk >> 1) & 31)) : sk;
        tmp[j] = f2bf(W[((long)(p * K + k)) * N + n]);
    }
    unsigned short* dst = out + ((((long)(p * CH + c) * 4 + u) * N + n) * 8);
    *reinterpret_cast<uint4*>(dst) = *reinterpret_cast<const uint4*>(tmp);
}

extern "C" __global__ __launch_bounds__(256)
void prep_all(const float* __restrict__ W1, const float* __restrict__ W2,
              const float* __restrict__ W3, const float* __restrict__ W4,
              unsigned short* __restrict__ ws)
{
    int b = blockIdx.x, t = threadIdx.x;
    if      (b < 1024) prep_body<128, 256, false>(W1, ws + WS1, b,        t);
    else if (b < 3072) prep_body<256, 256, true >(W2, ws + WS2, b - 1024, t);
    else if (b < 5120) prep_body<256, 256, true >(W3, ws + WS3, b - 3072, t);
    else               prep_body<256, 32,  true >(W4, ws + WS4, b - 5120, t);
}

// -------- async global->LDS staging: nbytes contiguous, 16B/lane --------
__device__ __forceinline__ void stage(char* lds, const char* src, int nbytes, int tid)
{
    const int lnoff = (tid & 63) * 16;
    const int off   = (tid >> 6) * 1024 + lnoff;
    for (int i = off; i < nbytes; i += 4096) {   // wave-uniform trip count (lnoff < 1024)
        __builtin_amdgcn_global_load_lds(
            (const __attribute__((address_space(1))) unsigned int*)(const void*)(src + i),
            (__attribute__((address_space(3))) unsigned int*)(void*)(lds + (i - lnoff)),
            16, 0, 0);
    }
}

// -------- one 256-wide fused layer (32x32x16 MFMA, 2x2 tiles/wave) --------
// KCH counts 16-k half-chunks (8 KB each). Output written to X in
// pi-permuted column order as packed bf16x2 (b32 stores, conflict-free).
template<int KCH>
__device__ __forceinline__ void layer256(
    unsigned short* __restrict__ X,
    char* __restrict__ Wb0, char* __restrict__ Wb1,
    const char* __restrict__ wsrc,
    const char* __restrict__ nsrc, int nbytes,
    const float* __restrict__ bp, const float* __restrict__ gp, const float* __restrict__ bep,
    float2* __restrict__ part, float2* __restrict__ stats,
    int tid, bool elu)
{
    const int w  = tid >> 6;         // wave 0..3 -> col stripe 64w..64w+63
    const int l5 = tid & 31;
    const int h  = (tid & 63) >> 5;  // lane half

    f32x16 acc[2][2];
#pragma unroll
    for (int rt = 0; rt < 2; ++rt)
#pragma unroll
        for (int ct = 0; ct < 2; ++ct)
#pragma unroll
            for (int r = 0; r < 16; ++r) acc[rt][ct][r] = 0.f;

#pragma unroll
    for (int c = 0; c < KCH; ++c) {
        const char* nx = (c + 1 < KCH) ? (wsrc + (long)(c + 1) * 8192) : nsrc;
        int nb         = (c + 1 < KCH) ? 8192 : nbytes;
        stage((c & 1) ? Wb0 : Wb1, nx, nb, tid);

        const char* wc = (c & 1) ? Wb1 : Wb0;
        const int k0 = c * 16 + h * 8;
        bf16x8 a0 = *(const bf16x8*)(X + l5 * XSTRIDE + k0);
        bf16x8 a1 = *(const bf16x8*)(X + (32 + l5) * XSTRIDE + k0);
        const char* bb = wc + h * 4096;               // k-octet u = h within half-chunk
        bf16x8 b0 = *(const bf16x8*)(bb + (w * 64 + l5) * 16);
        bf16x8 b1 = *(const bf16x8*)(bb + (w * 64 + 32 + l5) * 16);
        acc[0][0] = __builtin_amdgcn_mfma_f32_32x32x16_bf16(a0, b0, acc[0][0], 0, 0, 0);
        acc[1][0] = __builtin_amdgcn_mfma_f32_32x32x16_bf16(a1, b0, acc[1][0], 0, 0, 0);
        acc[0][1] = __builtin_amdgcn_mfma_f32_32x32x16_bf16(a0, b1, acc[0][1], 0, 0, 0);
        acc[1][1] = __builtin_amdgcn_mfma_f32_32x32x16_bf16(a1, b1, acc[1][1], 0, 0, 0);
        __syncthreads();   // drains prefetch (vmcnt) + protects buffer reuse
    }

    // ---- epilogue: bias, GroupNorm over 256, optional ELU, in-place X update ----
    // Thread's two cols n0, n1 land at adjacent permuted positions 2*l5, 2*l5+1.
    const int n0 = w * 64 + l5, n1 = n0 + 32;
    const int pos = w * 64 + 2 * l5;                  // permuted, even -> 4B aligned
    const float bb0 = bp[n0], bb1 = bp[n1];
#pragma unroll
    for (int rt = 0; rt < 2; ++rt)
#pragma unroll
        for (int r = 0; r < 16; ++r) { acc[rt][0][r] += bb0; acc[rt][1][r] += bb1; }

    // pass 1: write pre-GN y (packed bf16x2) to X.
    // NO barrier before pass 2: wave w writes stripe w and pass 2 reads ONLY
    // stripe w -> purely intra-wave DS dependency (HW orders same-wave DS ops).
#pragma unroll
    for (int rt = 0; rt < 2; ++rt)
#pragma unroll
        for (int r = 0; r < 16; ++r) {
            const int row = rt * 32 + (r & 3) + 8 * (r >> 2) + 4 * h;
            *reinterpret_cast<unsigned*>(X + row * XSTRIDE + pos) =
                pack_bf16_rne(acc[rt][0][r], acc[rt][1][r]);
        }

    // pass 2: per-row (s, s2): wave w sums its 64-position stripe of row `lane`
    {
        const int lane = tid & 63;
        float s = 0.f, s2 = 0.f;
#pragma unroll
        for (int j8 = 0; j8 < 8; ++j8) {
            bf16x8 v8 = *(const bf16x8*)(X + lane * XSTRIDE + w * 64 + j8 * 8);
#pragma unroll
            for (int e = 0; e < 8; ++e) { float v = (float)v8[e]; s += v; s2 = fmaf(v, v, s2); }
        }
        part[lane * 4 + w] = make_float2(s, s2);
    }
    __syncthreads();
    if (w == 0) {
        const int lane = tid & 63;
        float2 p0 = part[lane * 4 + 0], p1 = part[lane * 4 + 1];
        float2 p2 = part[lane * 4 + 2], p3 = part[lane * 4 + 3];
        float s  = p0.x + p1.x + p2.x + p3.x;
        float s2 = p0.y + p1.y + p2.y + p3.y;
        float mu  = s * (1.f / 256.f);
        float var = s2 * (1.f / 256.f) - mu * mu;
        stats[lane] = make_float2(mu, rsqrtf(var + 1e-5f));
    }
    __syncthreads();

    const float g0 = gp[n0], g1 = gp[n1], be0 = bep[n0], be1 = bep[n1];
#pragma unroll
    for (int rt = 0; rt < 2; ++rt)
#pragma unroll
        for (int r = 0; r < 16; ++r) {
            const int row = rt * 32 + (r & 3) + 8 * (r >> 2) + 4 * h;
            float2 st = stats[row];                  // LDS broadcast
            float v0 = (acc[rt][0][r] - st.x) * st.y * g0 + be0;
            float v1 = (acc[rt][1][r] - st.x) * st.y * g1 + be1;
            if (elu) { v0 = elu_asm(v0); v1 = elu_asm(v1); }
            *reinterpret_cast<unsigned*>(X + row * XSTRIDE + pos) = pack_bf16_rne(v0, v1);
        }
    __syncthreads();
}

// -------- final layer: N=32, 16x16x32 MFMA, GN via butterfly, fp32 out --------
// Input X is pi-permuted (layer-3 output); ws4's B image is k-permuted to match.
__device__ __forceinline__ void layer32(
    const unsigned short* __restrict__ X,
    char* __restrict__ Wb0, char* __restrict__ Wb1,
    const char* __restrict__ wsrc,
    const float* __restrict__ bp, const float* __restrict__ gp, const float* __restrict__ bep,
    float* __restrict__ outg, int bbase, int p, int tid)
{
    const int w = tid >> 6, lane = tid & 63, ln = lane & 15, quad = lane >> 4;
    f32x4 acc[2];
#pragma unroll
    for (int nt = 0; nt < 2; ++nt)
#pragma unroll
        for (int r = 0; r < 4; ++r) acc[nt][r] = 0.f;

#pragma unroll
    for (int c = 0; c < 8; ++c) {
        if (c < 7) stage((c & 1) ? Wb0 : Wb1, wsrc + (long)(c + 1) * 2048, 2048, tid);
        const char* wc = (c & 1) ? Wb1 : Wb0;
        bf16x8 a  = *(const bf16x8*)(X + (16 * w + ln) * XSTRIDE + c * 32 + quad * 8);
        bf16x8 b0 = *(const bf16x8*)(wc + quad * 512 + ln * 16);
        bf16x8 b1 = *(const bf16x8*)(wc + quad * 512 + (16 + ln) * 16);
        acc[0] = __builtin_amdgcn_mfma_f32_16x16x32_bf16(a, b0, acc[0], 0, 0, 0);
        acc[1] = __builtin_amdgcn_mfma_f32_16x16x32_bf16(a, b1, acc[1], 0, 0, 0);
        __syncthreads();
    }

    const float bb0 = bp[ln], bb1 = bp[16 + ln];
    const float g0 = gp[ln], g1 = gp[16 + ln], be0 = bep[ln], be1 = bep[16 + ln];
#pragma unroll
    for (int r = 0; r < 4; ++r) {
        float y0 = acc[0][r] + bb0, y1 = acc[1][r] + bb1;
        float s = y0 + y1, s2 = y0 * y0 + y1 * y1;
        s += __shfl_xor(s, 1);  s2 += __shfl_xor(s2, 1);
        s += __shfl_xor(s, 2);  s2 += __shfl_xor(s2, 2);
        s += __shfl_xor(s, 4);  s2 += __shfl_xor(s2, 4);
        s += __shfl_xor(s, 8);  s2 += __shfl_xor(s2, 8);
        float mu  = s * (1.f / 32.f);
        float var = s2 * (1.f / 32.f) - mu * mu;
        float rs  = rsqrtf(var + 1e-5f);
        const int row = bbase + 16 * w + quad * 4 + r;
        float* o = outg + ((long)row * P_ + p) * ACTD_;
        o[ln]      = (y0 - mu) * rs * g0 + be0;
        o[16 + ln] = (y1 - mu) * rs * g1 + be1;
    }
}

extern "C" __global__ void __launch_bounds__(256, 3)
policy_fused(const float* __restrict__ obs,
             const unsigned short* __restrict__ wbf,
             const float* __restrict__ b1, const float* __restrict__ g1, const float* __restrict__ be1,
             const float* __restrict__ b2, const float* __restrict__ g2, const float* __restrict__ be2,
             const float* __restrict__ b3, const float* __restrict__ g3, const float* __restrict__ be3,
             const float* __restrict__ b4, const float* __restrict__ g4, const float* __restrict__ be4,
             float* __restrict__ out)
{
    __shared__ __align__(16) unsigned short X[64 * XSTRIDE];   // 33.8 KB
    __shared__ __align__(16) char Wbuf0[8192];
    __shared__ __align__(16) char Wbuf1[8192];
    __shared__ float2 part[64 * 4];
    __shared__ float2 stats[64];
    // total ~52.7 KB -> 3 blocks/CU

    const int tid = threadIdx.x;
    const int bx  = blockIdx.x;
    const int p     = ((bx & 7) << 3) | ((bx >> 3) & 7);   // XCD-locality swizzle
    const int bbase = (bx >> 6) * 64;

    const char* ws1 = (const char*)(wbf + WS1 + (long)p * (128 * 256));
    const char* ws2 = (const char*)(wbf + WS2 + (long)p * (256 * 256));
    const char* ws3 = (const char*)(wbf + WS3 + (long)p * (256 * 256));
    const char* ws4 = (const char*)(wbf + WS4 + (long)p * (256 * 32));

    stage(Wbuf0, ws1, 8192, tid);   // L1 half-chunk 0, overlaps obs staging

    // obs staging: layer-1 input keeps ORIGINAL column order (W1 unpermuted)
    for (int idx = tid; idx < 64 * 32; idx += 256) {
        int row = idx >> 5, c4 = idx & 31;
        float4 v = *reinterpret_cast<const float4*>(obs + (long)(bbase + row) * OBS_ + c4 * 4);
        uint2 pk;
        pk.x = pack_bf16_rne(v.x, v.y);
        pk.y = pack_bf16_rne(v.z, v.w);
        *reinterpret_cast<uint2*>(X + row * XSTRIDE + c4 * 4) = pk;
    }
    __syncthreads();

    layer256<8>(X, Wbuf0, Wbuf1, ws1, ws2, 8192,
                b1 + p * 256, g1 + p * 256, be1 + p * 256, part, stats, tid, true);
    layer256<16>(X, Wbuf0, Wbuf1, ws2, ws3, 8192,
                 b2 + p * 256, g2 + p * 256, be2 + p * 256, part, stats, tid, true);
    layer256<16>(X, Wbuf0, Wbuf1, ws3, ws4, 2048,
                 b3 + p * 256, g3 + p * 256, be3 + p * 256, part, stats, tid, true);
    layer32(X, Wbuf0, Wbuf1, ws4,
            b4 + p * 32, g4 + p * 32, be4 + p * 32, out, bbase, p, tid);
}

extern "C" void kernel_launch(void* const* d_in, const int* in_sizes, int n_in,
                              void* d_out, int out_size, void* d_ws, size_t ws_size,
                              hipStream_t stream)
{
    const float* obs = (const float*)d_in[0];
    const float* W1  = (const float*)d_in[1];
    const float* b1  = (const float*)d_in[2];
    const float* g1  = (const float*)d_in[3];
    const float* be1 = (const float*)d_in[4];
    const float* W2  = (const float*)d_in[5];
    const float* b2  = (const float*)d_in[6];
    const float* g2  = (const float*)d_in[7];
    const float* be2 = (const float*)d_in[8];
    const float* W3  = (const float*)d_in[9];
    const float* b3  = (const float*)d_in[10];
    const float* g3  = (const float*)d_in[11];
    const float* be3 = (const float*)d_in[12];
    const float* W4  = (const float*)d_in[13];
    const float* b4  = (const float*)d_in[14];
    const float* g4  = (const float*)d_in[15];
    const float* be4 = (const float*)d_in[16];
    float* out = (float*)d_out;
    unsigned short* ws = (unsigned short*)d_ws;

    hipLaunchKernelGGL(prep_all, dim3(5376), dim3(256), 0, stream, W1, W2, W3, W4, ws);

    hipLaunchKernelGGL(policy_fused, dim3(4096), dim3(256), 0, stream,
                       obs, ws,
                       b1, g1, be1, b2, g2, be2, b3, g3, be3, b4, g4, be4, out);
}

// Round 11
// 283.207 us; speedup vs baseline: 1.1095x; 1.1095x over previous
//
#include <hip/hip_runtime.h>

#define B_    4096
#define P_    64
#define OBS_  128
#define HID_  256
#define ACTD_ 32

typedef __attribute__((ext_vector_type(8)))  __bf16 bf16x8;
typedef __attribute__((ext_vector_type(2)))  __bf16 bf16x2_t;
typedef __attribute__((ext_vector_type(4)))  float  f32x4;
typedef __attribute__((ext_vector_type(16))) float  f32x16;

#define XSTRIDE 264   // bf16 elems; 33 16B-units/row -> odd mod 8 -> bank-group-balanced

// ws layout (bf16 elems)
#define WS1 0L
#define WS2 2097152L
#define WS3 6291456L
#define WS4 10485760L

#if defined(__has_builtin)
#if __has_builtin(__builtin_amdgcn_cvt_pk_bf16_f32)
#define HAVE_CVT_PK_BF16 1
#endif
#endif
#ifndef HAVE_CVT_PK_BF16
#define HAVE_CVT_PK_BF16 0
#endif

// Integer RNE fp32->bf16. PROVEN on HW (rounds 2/6-10, absmax 0.0390625).
__device__ __forceinline__ unsigned short f2bf(float x) {
    unsigned u = __builtin_bit_cast(unsigned, x);
    u = (u + 0x7fffu + ((u >> 16) & 1u)) >> 16;   // RNE
    return (unsigned short)u;
}

// Pack two fp32 -> bf16x2 (RNE): lo16 = bf16(a), hi16 = bf16(b).
__device__ __forceinline__ unsigned pack_bf16_rne(float a, float b) {
#if HAVE_CVT_PK_BF16
    bf16x2_t p = __builtin_amdgcn_cvt_pk_bf16_f32(a, b);
    return __builtin_bit_cast(unsigned, p);
#else
    unsigned ua = __builtin_bit_cast(unsigned, a);
    unsigned ub = __builtin_bit_cast(unsigned, b);
    ua = ua + 0x7fffu + ((ua >> 16) & 1u);
    ub = ub + 0x7fffu + ((ub >> 16) & 1u);
    return __builtin_amdgcn_perm(ub, ua, 0x07060302u);
#endif
}

// ELU via raw inline asm — PROVEN rounds 8/9/10. Compiler-generated
// unconditional-exp+select ELUs miscompute (rounds 3/4/5); do not revert.
__device__ __forceinline__ float elu_asm(float v) {
    float r;
    asm volatile(
        "v_mul_f32 %0, 0x3fb8aa3b, %1\n\t"
        "v_exp_f32 %0, %0\n\t"
        "s_nop 1\n\t"
        "v_add_f32 %0, -1.0, %0\n\t"
        "v_cmp_lt_f32 vcc, 0, %1\n\t"
        "v_cndmask_b32 %0, %0, %1, vcc"
        : "=&v"(r) : "v"(v) : "vcc");
    return r;
}

// -------- fused weight prep: fp32 [P][K][N] -> bf16 [P][K/32][4 u][N][8 j] --------
// Same image as rounds 2-10; now read directly by per-lane global loads.
template<int K, int N, bool PERM>
__device__ __forceinline__ void prep_body(const float* __restrict__ W,
                                          unsigned short* __restrict__ out,
                                          int b, int t)
{
    constexpr int CH = K / 32;
    int tid  = b * 256 + t;
    int n    = tid % N;
    int rest = tid / N;
    int u    = rest % 4;
    rest    /= 4;
    int c    = rest % CH;
    int p    = rest / CH;
    unsigned short tmp[8];
#pragma unroll
    for (int j = 0; j < 8; ++j) {
        int sk = c * 32 + u * 8 + j;
        int k  = PERM ? ((sk & ~63) | ((sk & 1) << 5) | ((sk >> 1) & 31)) : sk;
        tmp[j] = f2bf(W[((long)(p * K + k)) * N + n]);
    }
    unsigned short* dst = out + ((((long)(p * CH + c) * 4 + u) * N + n) * 8);
    *reinterpret_cast<uint4*>(dst) = *reinterpret_cast<const uint4*>(tmp);
}

extern "C" __global__ __launch_bounds__(256)
void prep_all(const float* __restrict__ W1, const float* __restrict__ W2,
              const float* __restrict__ W3, const float* __restrict__ W4,
              unsigned short* __restrict__ ws)
{
    int b = blockIdx.x, t = threadIdx.x;
    if      (b < 1024) prep_body<128, 256, false>(W1, ws + WS1, b,        t);
    else if (b < 3072) prep_body<256, 256, true >(W2, ws + WS2, b - 1024, t);
    else if (b < 5120) prep_body<256, 256, true >(W3, ws + WS3, b - 3072, t);
    else               prep_body<256, 32,  true >(W4, ws + WS4, b - 5120, t);
}

// -------- one 256-wide fused layer (32x32x16 MFMA, 2x2 tiles/wave) --------
// B-fragments loaded DIRECTLY global->VGPR (no LDS staging, no k-loop
// barriers): within a block, wave w only reads col stripe 64w..64w+63 —
// LDS gave zero intra-block sharing; L2 handles inter-block reuse.
// Address check vs round-9 LDS path: elem idx (c*512 + h*256 + w*64 + l5)
// *16B == wsrc + c*8192 + h*4096 + (w*64+l5)*16  ✓ bit-identical operands.
template<int KCH>
__device__ __forceinline__ void layer256(
    unsigned short* __restrict__ X,
    const char* __restrict__ wsrc,
    const float* __restrict__ bp, const float* __restrict__ gp, const float* __restrict__ bep,
    float2* __restrict__ part, float2* __restrict__ stats,
    int tid, bool elu)
{
    const int w  = tid >> 6;         // wave 0..3 -> col stripe 64w..64w+63
    const int l5 = tid & 31;
    const int h  = (tid & 63) >> 5;  // lane half

    const bf16x8* __restrict__ Bp = (const bf16x8*)wsrc + (h * 256 + w * 64 + l5);

    f32x16 acc[2][2];
#pragma unroll
    for (int rt = 0; rt < 2; ++rt)
#pragma unroll
        for (int ct = 0; ct < 2; ++ct)
#pragma unroll
            for (int r = 0; r < 16; ++r) acc[rt][ct][r] = 0.f;

#pragma unroll
    for (int c = 0; c < KCH; ++c) {
        const int k0 = c * 16 + h * 8;
        bf16x8 a0 = *(const bf16x8*)(X + l5 * XSTRIDE + k0);
        bf16x8 a1 = *(const bf16x8*)(X + (32 + l5) * XSTRIDE + k0);
        bf16x8 b0 = Bp[c * 512];
        bf16x8 b1 = Bp[c * 512 + 32];
        acc[0][0] = __builtin_amdgcn_mfma_f32_32x32x16_bf16(a0, b0, acc[0][0], 0, 0, 0);
        acc[1][0] = __builtin_amdgcn_mfma_f32_32x32x16_bf16(a1, b0, acc[1][0], 0, 0, 0);
        acc[0][1] = __builtin_amdgcn_mfma_f32_32x32x16_bf16(a0, b1, acc[0][1], 0, 0, 0);
        acc[1][1] = __builtin_amdgcn_mfma_f32_32x32x16_bf16(a1, b1, acc[1][1], 0, 0, 0);
    }
    __syncthreads();   // ALL waves' A-reads of X done before epilogue rewrites X

    // ---- epilogue: bias, GroupNorm over 256, optional ELU, in-place X update ----
    const int n0 = w * 64 + l5, n1 = n0 + 32;
    const int pos = w * 64 + 2 * l5;                  // pi-permuted, even -> 4B aligned
    const float bb0 = bp[n0], bb1 = bp[n1];
#pragma unroll
    for (int rt = 0; rt < 2; ++rt)
#pragma unroll
        for (int r = 0; r < 16; ++r) { acc[rt][0][r] += bb0; acc[rt][1][r] += bb1; }

    // pass 1: write pre-GN y (packed bf16x2) to X; intra-wave only vs pass 2.
#pragma unroll
    for (int rt = 0; rt < 2; ++rt)
#pragma unroll
        for (int r = 0; r < 16; ++r) {
            const int row = rt * 32 + (r & 3) + 8 * (r >> 2) + 4 * h;
            *reinterpret_cast<unsigned*>(X + row * XSTRIDE + pos) =
                pack_bf16_rne(acc[rt][0][r], acc[rt][1][r]);
        }

    // pass 2: per-row (s, s2): wave w sums its own 64-position stripe of row `lane`
    {
        const int lane = tid & 63;
        float s = 0.f, s2 = 0.f;
#pragma unroll
        for (int j8 = 0; j8 < 8; ++j8) {
            bf16x8 v8 = *(const bf16x8*)(X + lane * XSTRIDE + w * 64 + j8 * 8);
#pragma unroll
            for (int e = 0; e < 8; ++e) { float v = (float)v8[e]; s += v; s2 = fmaf(v, v, s2); }
        }
        part[lane * 4 + w] = make_float2(s, s2);
    }
    __syncthreads();
    if (w == 0) {
        const int lane = tid & 63;
        float2 p0 = part[lane * 4 + 0], p1 = part[lane * 4 + 1];
        float2 p2 = part[lane * 4 + 2], p3 = part[lane * 4 + 3];
        float s  = p0.x + p1.x + p2.x + p3.x;
        float s2 = p0.y + p1.y + p2.y + p3.y;
        float mu  = s * (1.f / 256.f);
        float var = s2 * (1.f / 256.f) - mu * mu;
        stats[lane] = make_float2(mu, rsqrtf(var + 1e-5f));
    }
    __syncthreads();

    const float g0 = gp[n0], g1 = gp[n1], be0 = bep[n0], be1 = bep[n1];
#pragma unroll
    for (int rt = 0; rt < 2; ++rt)
#pragma unroll
        for (int r = 0; r < 16; ++r) {
            const int row = rt * 32 + (r & 3) + 8 * (r >> 2) + 4 * h;
            float2 st = stats[row];
            float v0 = (acc[rt][0][r] - st.x) * st.y * g0 + be0;
            float v1 = (acc[rt][1][r] - st.x) * st.y * g1 + be1;
            if (elu) { v0 = elu_asm(v0); v1 = elu_asm(v1); }
            *reinterpret_cast<unsigned*>(X + row * XSTRIDE + pos) = pack_bf16_rne(v0, v1);
        }
    __syncthreads();   // stripe writes visible before next layer's full-X A-reads
}

// -------- final layer: N=32, 16x16x32 MFMA, direct-global B, no barriers --------
// Wave w reads only its own X rows 16w..16w+15 (written under the layer-3
// epilogue barrier). B elem idx c*128 + quad*32 + ln (+16) == round-9 address.
__device__ __forceinline__ void layer32(
    const unsigned short* __restrict__ X,
    const char* __restrict__ wsrc,
    const float* __restrict__ bp, const float* __restrict__ gp, const float* __restrict__ bep,
    float* __restrict__ outg, int bbase, int p, int tid)
{
    const int w = tid >> 6, lane = tid & 63, ln = lane & 15, quad = lane >> 4;
    const bf16x8* __restrict__ Bp = (const bf16x8*)wsrc + (quad * 32 + ln);

    f32x4 acc[2];
#pragma unroll
    for (int nt = 0; nt < 2; ++nt)
#pragma unroll
        for (int r = 0; r < 4; ++r) acc[nt][r] = 0.f;

#pragma unroll
    for (int c = 0; c < 8; ++c) {
        bf16x8 a  = *(const bf16x8*)(X + (16 * w + ln) * XSTRIDE + c * 32 + quad * 8);
        bf16x8 b0 = Bp[c * 128];
        bf16x8 b1 = Bp[c * 128 + 16];
        acc[0] = __builtin_amdgcn_mfma_f32_16x16x32_bf16(a, b0, acc[0], 0, 0, 0);
        acc[1] = __builtin_amdgcn_mfma_f32_16x16x32_bf16(a, b1, acc[1], 0, 0, 0);
    }

    const float bb0 = bp[ln], bb1 = bp[16 + ln];
    const float g0 = gp[ln], g1 = gp[16 + ln], be0 = bep[ln], be1 = bep[16 + ln];
#pragma unroll
    for (int r = 0; r < 4; ++r) {
        float y0 = acc[0][r] + bb0, y1 = acc[1][r] + bb1;
        float s = y0 + y1, s2 = y0 * y0 + y1 * y1;
        s += __shfl_xor(s, 1);  s2 += __shfl_xor(s2, 1);
        s += __shfl_xor(s, 2);  s2 += __shfl_xor(s2, 2);
        s += __shfl_xor(s, 4);  s2 += __shfl_xor(s2, 4);
        s += __shfl_xor(s, 8);  s2 += __shfl_xor(s2, 8);
        float mu  = s * (1.f / 32.f);
        float var = s2 * (1.f / 32.f) - mu * mu;
        float rs  = rsqrtf(var + 1e-5f);
        const int row = bbase + 16 * w + quad * 4 + r;
        float* o = outg + ((long)row * P_ + p) * ACTD_;
        o[ln]      = (y0 - mu) * rs * g0 + be0;
        o[16 + ln] = (y1 - mu) * rs * g1 + be1;
    }
}

extern "C" __global__ void __launch_bounds__(256, 4)
policy_fused(const float* __restrict__ obs,
             const unsigned short* __restrict__ wbf,
             const float* __restrict__ b1, const float* __restrict__ g1, const float* __restrict__ be1,
             const float* __restrict__ b2, const float* __restrict__ g2, const float* __restrict__ be2,
             const float* __restrict__ b3, const float* __restrict__ g3, const float* __restrict__ be3,
             const float* __restrict__ b4, const float* __restrict__ g4, const float* __restrict__ be4,
             float* __restrict__ out)
{
    __shared__ __align__(16) unsigned short X[64 * XSTRIDE];   // 33.8 KB
    __shared__ float2 part[64 * 4];
    __shared__ float2 stats[64];
    // total ~36.4 KB -> 4 blocks/CU (VGPR must stay <=128)

    const int tid = threadIdx.x;
    const int bx  = blockIdx.x;
    const int p     = ((bx & 7) << 3) | ((bx >> 3) & 7);   // XCD-locality swizzle
    const int bbase = (bx >> 6) * 64;

    const char* ws1 = (const char*)(wbf + WS1 + (long)p * (128 * 256));
    const char* ws2 = (const char*)(wbf + WS2 + (long)p * (256 * 256));
    const char* ws3 = (const char*)(wbf + WS3 + (long)p * (256 * 256));
    const char* ws4 = (const char*)(wbf + WS4 + (long)p * (256 * 32));

    // obs staging: layer-1 input keeps ORIGINAL column order (W1 unpermuted)
    for (int idx = tid; idx < 64 * 32; idx += 256) {
        int row = idx >> 5, c4 = idx & 31;
        float4 v = *reinterpret_cast<const float4*>(obs + (long)(bbase + row) * OBS_ + c4 * 4);
        uint2 pk;
        pk.x = pack_bf16_rne(v.x, v.y);
        pk.y = pack_bf16_rne(v.z, v.w);
        *reinterpret_cast<uint2*>(X + row * XSTRIDE + c4 * 4) = pk;
    }
    __syncthreads();

    layer256<8>(X, ws1, b1 + p * 256, g1 + p * 256, be1 + p * 256, part, stats, tid, true);
    layer256<16>(X, ws2, b2 + p * 256, g2 + p * 256, be2 + p * 256, part, stats, tid, true);
    layer256<16>(X, ws3, b3 + p * 256, g3 + p * 256, be3 + p * 256, part, stats, tid, true);
    layer32(X, ws4, b4 + p * 32, g4 + p * 32, be4 + p * 32, out, bbase, p, tid);
}

extern "C" void kernel_launch(void* const* d_in, const int* in_sizes, int n_in,
                              void* d_out, int out_size, void* d_ws, size_t ws_size,
                              hipStream_t stream)
{
    const float* obs = (const float*)d_in[0];
    const float* W1  = (const float*)d_in[1];
    const float* b1  = (const float*)d_in[2];
    const float* g1  = (const float*)d_in[3];
    const float* be1 = (const float*)d_in[4];
    const float* W2  = (const float*)d_in[5];
    const float* b2  = (const float*)d_in[6];
    const float* g2  = (const float*)d_in[7];
    const float* be2 = (const float*)d_in[8];
    const float* W3  = (const float*)d_in[9];
    const float* b3  = (const float*)d_in[10];
    const float* g3  = (const float*)d_in[11];
    const float* be3 = (const float*)d_in[12];
    const float* W4  = (const float*)d_in[13];
    const float* b4  = (const float*)d_in[14];
    const float* g4  = (const float*)d_in[15];
    const float* be4 = (const float*)d_in[16];
    float* out = (float*)d_out;
    unsigned short* ws = (unsigned short*)d_ws;

    hipLaunchKernelGGL(prep_all, dim3(5376), dim3(256), 0, stream, W1, W2, W3, W4, ws);

    hipLaunchKernelGGL(policy_fused, dim3(4096), dim3(256), 0, stream,
                       obs, ws,
                       b1, g1, be1, b2, g2, be2, b3, g3, be3, b4, g4, be4, out);
}

// Round 12
// 276.377 us; speedup vs baseline: 1.1369x; 1.0247x over previous
//
#include <hip/hip_runtime.h>

#define B_    4096
#define P_    64
#define OBS_  128
#define HID_  256
#define ACTD_ 32

typedef __attribute__((ext_vector_type(8)))  __bf16 bf16x8;
typedef __attribute__((ext_vector_type(2)))  __bf16 bf16x2_t;
typedef __attribute__((ext_vector_type(2)))  float  f32x2;
typedef __attribute__((ext_vector_type(4)))  float  f32x4;
typedef __attribute__((ext_vector_type(16))) float  f32x16;

#define XSTRIDE 264   // bf16 elems; 16B-aligned rows, bank-group-balanced

// ws layout (bf16 elems)
#define WS1 0L
#define WS2 2097152L
#define WS3 6291456L
#define WS4 10485760L

#if defined(__has_builtin)
#if __has_builtin(__builtin_amdgcn_cvt_pk_bf16_f32)
#define HAVE_CVT_PK_BF16 1
#endif
#endif
#ifndef HAVE_CVT_PK_BF16
#define HAVE_CVT_PK_BF16 0
#endif

// Integer RNE fp32->bf16. PROVEN on HW (rounds 2/6-11, absmax 0.0390625).
__device__ __forceinline__ unsigned short f2bf(float x) {
    unsigned u = __builtin_bit_cast(unsigned, x);
    u = (u + 0x7fffu + ((u >> 16) & 1u)) >> 16;   // RNE
    return (unsigned short)u;
}

// Pack two fp32 -> bf16x2 (RNE): lo16 = bf16(a), hi16 = bf16(b).
__device__ __forceinline__ unsigned pack_bf16_rne(float a, float b) {
#if HAVE_CVT_PK_BF16
    bf16x2_t p = __builtin_amdgcn_cvt_pk_bf16_f32(a, b);
    return __builtin_bit_cast(unsigned, p);
#else
    unsigned ua = __builtin_bit_cast(unsigned, a);
    unsigned ub = __builtin_bit_cast(unsigned, b);
    ua = ua + 0x7fffu + ((ua >> 16) & 1u);
    ub = ub + 0x7fffu + ((ub >> 16) & 1u);
    return __builtin_amdgcn_perm(ub, ua, 0x07060302u);
#endif
}

// Paired ELU via raw inline asm — same ops per element as the PROVEN round-8
// elu_asm (rounds 8-11), two elements per block: back-to-back exps + s_nop 0
// cover the trans-op hazard (>=3 issue slots before each consumer).
// Compiler-generated unconditional-exp+select ELUs miscompute (r3/4/5); keep asm.
__device__ __forceinline__ void elu2_asm(float &a, float &b) {
    float ra, rb;
    asm volatile(
        "v_mul_f32 %0, 0x3fb8aa3b, %2\n\t"
        "v_mul_f32 %1, 0x3fb8aa3b, %3\n\t"
        "v_exp_f32 %0, %0\n\t"
        "v_exp_f32 %1, %1\n\t"
        "s_nop 0\n\t"
        "v_add_f32 %0, -1.0, %0\n\t"
        "v_add_f32 %1, -1.0, %1\n\t"
        "v_cmp_lt_f32 vcc, 0, %2\n\t"
        "v_cndmask_b32 %0, %0, %2, vcc\n\t"
        "v_cmp_lt_f32 vcc, 0, %3\n\t"
        "v_cndmask_b32 %1, %1, %3, vcc"
        : "=&v"(ra), "=&v"(rb) : "v"(a), "v"(b) : "vcc");
    a = ra; b = rb;
}

// -------- fused weight prep: fp32 [P][K][N] -> bf16 [P][K/32][4 u][N][8 j] --------
template<int K, int N, bool PERM>
__device__ __forceinline__ void prep_body(const float* __restrict__ W,
                                          unsigned short* __restrict__ out,
                                          int b, int t)
{
    constexpr int CH = K / 32;
    int tid  = b * 256 + t;
    int n    = tid % N;
    int rest = tid / N;
    int u    = rest % 4;
    rest    /= 4;
    int c    = rest % CH;
    int p    = rest / CH;
    unsigned short tmp[8];
#pragma unroll
    for (int j = 0; j < 8; ++j) {
        int sk = c * 32 + u * 8 + j;
        int k  = PERM ? ((sk & ~63) | ((sk & 1) << 5) | ((sk >> 1) & 31)) : sk;
        tmp[j] = f2bf(W[((long)(p * K + k)) * N + n]);
    }
    unsigned short* dst = out + ((((long)(p * CH + c) * 4 + u) * N + n) * 8);
    *reinterpret_cast<uint4*>(dst) = *reinterpret_cast<const uint4*>(tmp);
}

extern "C" __global__ __launch_bounds__(256)
void prep_all(const float* __restrict__ W1, const float* __restrict__ W2,
              const float* __restrict__ W3, const float* __restrict__ W4,
              unsigned short* __restrict__ ws)
{
    int b = blockIdx.x, t = threadIdx.x;
    if      (b < 1024) prep_body<128, 256, false>(W1, ws + WS1, b,        t);
    else if (b < 3072) prep_body<256, 256, true >(W2, ws + WS2, b - 1024, t);
    else if (b < 5120) prep_body<256, 256, true >(W3, ws + WS3, b - 3072, t);
    else               prep_body<256, 32,  true >(W4, ws + WS4, b - 5120, t);
}

// -------- one 256-wide fused layer (32x32x16 MFMA, 2x2 tiles/wave) --------
// B-fragments loaded DIRECTLY global->VGPR (round 11, proven): within a block,
// wave w only reads col stripe 64w..64w+63 — L2 handles inter-block reuse.
template<int KCH>
__device__ __forceinline__ void layer256(
    unsigned short* __restrict__ X,
    const char* __restrict__ wsrc,
    const float* __restrict__ bp, const float* __restrict__ gp, const float* __restrict__ bep,
    float2* __restrict__ part, float2* __restrict__ stats,
    int tid, bool elu)
{
    const int w  = tid >> 6;         // wave 0..3 -> col stripe 64w..64w+63
    const int l5 = tid & 31;
    const int h  = (tid & 63) >> 5;  // lane half

    const bf16x8* __restrict__ Bp = (const bf16x8*)wsrc + (h * 256 + w * 64 + l5);

    f32x16 acc[2][2];
#pragma unroll
    for (int rt = 0; rt < 2; ++rt)
#pragma unroll
        for (int ct = 0; ct < 2; ++ct)
#pragma unroll
            for (int r = 0; r < 16; ++r) acc[rt][ct][r] = 0.f;

#pragma unroll
    for (int c = 0; c < KCH; ++c) {
        const int k0 = c * 16 + h * 8;
        bf16x8 a0 = *(const bf16x8*)(X + l5 * XSTRIDE + k0);
        bf16x8 a1 = *(const bf16x8*)(X + (32 + l5) * XSTRIDE + k0);
        bf16x8 b0 = Bp[c * 512];
        bf16x8 b1 = Bp[c * 512 + 32];
        acc[0][0] = __builtin_amdgcn_mfma_f32_32x32x16_bf16(a0, b0, acc[0][0], 0, 0, 0);
        acc[1][0] = __builtin_amdgcn_mfma_f32_32x32x16_bf16(a1, b0, acc[1][0], 0, 0, 0);
        acc[0][1] = __builtin_amdgcn_mfma_f32_32x32x16_bf16(a0, b1, acc[0][1], 0, 0, 0);
        acc[1][1] = __builtin_amdgcn_mfma_f32_32x32x16_bf16(a1, b1, acc[1][1], 0, 0, 0);
    }
    __syncthreads();   // ALL waves' A-reads of X done before epilogue rewrites X

    // ---- epilogue: bias, GroupNorm over 256, optional ELU, in-place X update ----
    const int n0 = w * 64 + l5, n1 = n0 + 32;
    const int pos = w * 64 + 2 * l5;                  // pi-permuted, even -> 4B aligned
    const f32x2 bias2 = {bp[n0], bp[n1]};
#pragma unroll
    for (int rt = 0; rt < 2; ++rt)
#pragma unroll
        for (int r = 0; r < 16; ++r) {
            f32x2 t = {acc[rt][0][r], acc[rt][1][r]};
            t += bias2;                               // pk add (elementwise-identical)
            acc[rt][0][r] = t.x; acc[rt][1][r] = t.y;
        }

    // pass 1: write pre-GN y (packed bf16x2) to X; intra-wave only vs pass 2.
#pragma unroll
    for (int rt = 0; rt < 2; ++rt)
#pragma unroll
        for (int r = 0; r < 16; ++r) {
            const int row = rt * 32 + (r & 3) + 8 * (r >> 2) + 4 * h;
            *reinterpret_cast<unsigned*>(X + row * XSTRIDE + pos) =
                pack_bf16_rne(acc[rt][0][r], acc[rt][1][r]);
        }

    // pass 2: per-row (s, s2) over the wave's own 64-position stripe of row `lane`.
    // Two packed partials (S, S2) combined at the end — fp32 reassociation only.
    {
        const int lane = tid & 63;
        f32x2 S = {0.f, 0.f}, S2 = {0.f, 0.f};
#pragma unroll
        for (int j8 = 0; j8 < 8; ++j8) {
            bf16x8 v8 = *(const bf16x8*)(X + lane * XSTRIDE + w * 64 + j8 * 8);
#pragma unroll
            for (int e = 0; e < 4; ++e) {
                f32x2 vv = {(float)v8[2 * e], (float)v8[2 * e + 1]};
                S += vv;
                S2 = vv * vv + S2;                    // pk fma
            }
        }
        part[lane * 4 + w] = make_float2(S.x + S.y, S2.x + S2.y);
    }
    __syncthreads();
    if (w == 0) {
        const int lane = tid & 63;
        float2 p0 = part[lane * 4 + 0], p1 = part[lane * 4 + 1];
        float2 p2 = part[lane * 4 + 2], p3 = part[lane * 4 + 3];
        float s  = p0.x + p1.x + p2.x + p3.x;
        float s2 = p0.y + p1.y + p2.y + p3.y;
        float mu  = s * (1.f / 256.f);
        float var = s2 * (1.f / 256.f) - mu * mu;
        stats[lane] = make_float2(mu, rsqrtf(var + 1e-5f));
    }
    __syncthreads();

    const f32x2 gv2  = {gp[n0], gp[n1]};
    const f32x2 bev2 = {bep[n0], bep[n1]};
#pragma unroll
    for (int rt = 0; rt < 2; ++rt)
#pragma unroll
        for (int r = 0; r < 16; ++r) {
            const int row = rt * 32 + (r & 3) + 8 * (r >> 2) + 4 * h;
            float2 st = stats[row];
            f32x2 mu2 = {st.x, st.x};
            f32x2 rs2 = {st.y, st.y};
            f32x2 yv  = {acc[rt][0][r], acc[rt][1][r]};
            f32x2 zv  = (yv - mu2) * rs2 * gv2 + bev2;   // same ops as scalar path
            float v0 = zv.x, v1 = zv.y;
            if (elu) elu2_asm(v0, v1);
            *reinterpret_cast<unsigned*>(X + row * XSTRIDE + pos) = pack_bf16_rne(v0, v1);
        }
    __syncthreads();   // stripe writes visible before next layer's full-X A-reads
}

// -------- final layer: N=32, 16x16x32 MFMA, direct-global B, no barriers --------
__device__ __forceinline__ void layer32(
    const unsigned short* __restrict__ X,
    const char* __restrict__ wsrc,
    const float* __restrict__ bp, const float* __restrict__ gp, const float* __restrict__ bep,
    float* __restrict__ outg, int bbase, int p, int tid)
{
    const int w = tid >> 6, lane = tid & 63, ln = lane & 15, quad = lane >> 4;
    const bf16x8* __restrict__ Bp = (const bf16x8*)wsrc + (quad * 32 + ln);

    f32x4 acc[2];
#pragma unroll
    for (int nt = 0; nt < 2; ++nt)
#pragma unroll
        for (int r = 0; r < 4; ++r) acc[nt][r] = 0.f;

#pragma unroll
    for (int c = 0; c < 8; ++c) {
        bf16x8 a  = *(const bf16x8*)(X + (16 * w + ln) * XSTRIDE + c * 32 + quad * 8);
        bf16x8 b0 = Bp[c * 128];
        bf16x8 b1 = Bp[c * 128 + 16];
        acc[0] = __builtin_amdgcn_mfma_f32_16x16x32_bf16(a, b0, acc[0], 0, 0, 0);
        acc[1] = __builtin_amdgcn_mfma_f32_16x16x32_bf16(a, b1, acc[1], 0, 0, 0);
    }

    const float bb0 = bp[ln], bb1 = bp[16 + ln];
    const float g0 = gp[ln], g1 = gp[16 + ln], be0 = bep[ln], be1 = bep[16 + ln];
#pragma unroll
    for (int r = 0; r < 4; ++r) {
        float y0 = acc[0][r] + bb0, y1 = acc[1][r] + bb1;
        float s = y0 + y1, s2 = y0 * y0 + y1 * y1;
        s += __shfl_xor(s, 1);  s2 += __shfl_xor(s2, 1);
        s += __shfl_xor(s, 2);  s2 += __shfl_xor(s2, 2);
        s += __shfl_xor(s, 4);  s2 += __shfl_xor(s2, 4);
        s += __shfl_xor(s, 8);  s2 += __shfl_xor(s2, 8);
        float mu  = s * (1.f / 32.f);
        float var = s2 * (1.f / 32.f) - mu * mu;
        float rs  = rsqrtf(var + 1e-5f);
        const int row = bbase + 16 * w + quad * 4 + r;
        float* o = outg + ((long)row * P_ + p) * ACTD_;
        o[ln]      = (y0 - mu) * rs * g0 + be0;
        o[16 + ln] = (y1 - mu) * rs * g1 + be1;
    }
}

extern "C" __global__ void __launch_bounds__(256, 4)
policy_fused(const float* __restrict__ obs,
             const unsigned short* __restrict__ wbf,
             const float* __restrict__ b1, const float* __restrict__ g1, const float* __restrict__ be1,
             const float* __restrict__ b2, const float* __restrict__ g2, const float* __restrict__ be2,
             const float* __restrict__ b3, const float* __restrict__ g3, const float* __restrict__ be3,
             const float* __restrict__ b4, const float* __restrict__ g4, const float* __restrict__ be4,
             float* __restrict__ out)
{
    __shared__ __align__(16) unsigned short X[64 * XSTRIDE];   // 33.8 KB
    __shared__ float2 part[64 * 4];
    __shared__ float2 stats[64];
    // total ~36.4 KB -> 4 blocks/CU

    const int tid = threadIdx.x;
    const int bx  = blockIdx.x;
    const int p     = ((bx & 7) << 3) | ((bx >> 3) & 7);   // XCD-locality swizzle
    const int bbase = (bx >> 6) * 64;

    const char* ws1 = (const char*)(wbf + WS1 + (long)p * (128 * 256));
    const char* ws2 = (const char*)(wbf + WS2 + (long)p * (256 * 256));
    const char* ws3 = (const char*)(wbf + WS3 + (long)p * (256 * 256));
    const char* ws4 = (const char*)(wbf + WS4 + (long)p * (256 * 32));

    // obs staging: layer-1 input keeps ORIGINAL column order (W1 unpermuted)
    for (int idx = tid; idx < 64 * 32; idx += 256) {
        int row = idx >> 5, c4 = idx & 31;
        float4 v = *reinterpret_cast<const float4*>(obs + (long)(bbase + row) * OBS_ + c4 * 4);
        uint2 pk;
        pk.x = pack_bf16_rne(v.x, v.y);
        pk.y = pack_bf16_rne(v.z, v.w);
        *reinterpret_cast<uint2*>(X + row * XSTRIDE + c4 * 4) = pk;
    }
    __syncthreads();

    layer256<8>(X, ws1, b1 + p * 256, g1 + p * 256, be1 + p * 256, part, stats, tid, true);
    layer256<16>(X, ws2, b2 + p * 256, g2 + p * 256, be2 + p * 256, part, stats, tid, true);
    layer256<16>(X, ws3, b3 + p * 256, g3 + p * 256, be3 + p * 256, part, stats, tid, true);
    layer32(X, ws4, b4 + p * 32, g4 + p * 32, be4 + p * 32, out, bbase, p, tid);
}

extern "C" void kernel_launch(void* const* d_in, const int* in_sizes, int n_in,
                              void* d_out, int out_size, void* d_ws, size_t ws_size,
                              hipStream_t stream)
{
    const float* obs = (const float*)d_in[0];
    const float* W1  = (const float*)d_in[1];
    const float* b1  = (const float*)d_in[2];
    const float* g1  = (const float*)d_in[3];
    const float* be1 = (const float*)d_in[4];
    const float* W2  = (const float*)d_in[5];
    const float* b2  = (const float*)d_in[6];
    const float* g2  = (const float*)d_in[7];
    const float* be2 = (const float*)d_in[8];
    const float* W3  = (const float*)d_in[9];
    const float* b3  = (const float*)d_in[10];
    const float* g3  = (const float*)d_in[11];
    const float* be3 = (const float*)d_in[12];
    const float* W4  = (const float*)d_in[13];
    const float* b4  = (const float*)d_in[14];
    const float* g4  = (const float*)d_in[15];
    const float* be4 = (const float*)d_in[16];
    float* out = (float*)d_out;
    unsigned short* ws = (unsigned short*)d_ws;

    hipLaunchKernelGGL(prep_all, dim3(5376), dim3(256), 0, stream, W1, W2, W3, W4, ws);

    hipLaunchKernelGGL(policy_fused, dim3(4096), dim3(256), 0, stream,
                       obs, ws,
                       b1, g1, be1, b2, g2, be2, b3, g3, be3, b4, g4, be4, out);
}